// Round 10
// baseline (123.790 us; speedup 1.0000x reference)
//
#include <hip/hip_runtime.h>
#include <math.h>

#define NJ   24
#define TPB  256
#define IPT  16     // items per tile
#define ST   73     // float4 stride per item in LDS (24*3 + 1 pad)
#define NBLK 1024   // persistent blocks: 4 per CU

static constexpr int PAR[NJ] = {-1,0,0,0,1,2,3,4,5,6,7,8,9,9,9,12,13,14,16,17,18,19,20,21};

__device__ __forceinline__ void compute_tile(
    int tile, int Bn, int tid,
    const float* __restrict__ theta,
    const float* __restrict__ rest_pose,
    const float* __restrict__ bone_factor,
    float4* __restrict__ bf4)                 // LDS buffer for this tile
{
    const int it  = tid / 3;                   // item within tile (tid<48)
    const int row = tid % 3;
    const int gi  = tile * IPT + it;
    if (tid >= 48 || gi >= Bn) return;

    const float4* th4 = reinterpret_cast<const float4*>(theta) + (size_t)gi * 18;
    float4 tv[18];                             // one upfront burst: 1 miss latency
    #pragma unroll
    for (int i = 0; i < 18; ++i) tv[i] = th4[i];

    float4 rows_[NJ];                          // static-indexed; dead elems pruned
    #pragma unroll
    for (int sub = 0; sub < 3; ++sub) {
        float t[24];
        #pragma unroll
        for (int i = 0; i < 6; ++i) {
            const float4 v = tv[sub * 6 + i];
            t[i*4+0] = v.x; t[i*4+1] = v.y; t[i*4+2] = v.z; t[i*4+3] = v.w;
        }
        #pragma unroll
        for (int jj = 0; jj < 8; ++jj) {
            const int j = sub * 8 + jj;        // compile-time constant
            const float x = t[jj*3+0], y = t[jj*3+1], z = t[jj*3+2];
            const float ang = sqrtf(x*x + y*y + z*z + 1e-12f);
            const float inv = 1.0f / ang;
            const float ux = x*inv, uy = y*inv, uz = z*inv;
            const float s  = __sinf(ang);
            const float cs = __cosf(ang);
            const float ic = 1.0f - cs;
            const float xy = ic*ux*uy, xz = ic*ux*uz, yz = ic*uy*uz;
            const float sx = s*ux, sy = s*uy, sz = s*uz;
            const float R00 = cs + ic*ux*ux, R01 = xy - sz, R02 = xz + sy;
            const float R10 = xy + sz, R11 = cs + ic*uy*uy, R12 = yz - sx;
            const float R20 = xz - sy, R21 = yz + sx, R22 = cs + ic*uz*uz;

            float4 p; float bx, by, bz;
            if (j == 0) {
                p  = make_float4(row == 0 ? 1.f : 0.f,
                                 row == 1 ? 1.f : 0.f,
                                 row == 2 ? 1.f : 0.f, 0.f);
                bx = rest_pose[0]; by = rest_pose[1]; bz = rest_pose[2];
            } else {
                p = rows_[PAR[j]];
                float bfv = bone_factor[j - 1];
                bfv = sqrtf(bfv*bfv + 1e-36f);
                bx = (rest_pose[j*3+0] - rest_pose[PAR[j]*3+0]) * bfv;
                by = (rest_pose[j*3+1] - rest_pose[PAR[j]*3+1]) * bfv;
                bz = (rest_pose[j*3+2] - rest_pose[PAR[j]*3+2]) * bfv;
            }
            float4 nr;
            nr.x = p.x*R00 + p.y*R10 + p.z*R20;
            nr.y = p.x*R01 + p.y*R11 + p.z*R21;
            nr.z = p.x*R02 + p.y*R12 + p.z*R22;
            nr.w = p.x*bx  + p.y*by  + p.z*bz + p.w;
            rows_[j] = nr;
            bf4[it * ST + j * 3 + row] = nr;
        }
    }
}

__device__ __forceinline__ void flush_tile(
    int tile, int Bn, int tid,
    const float4* __restrict__ bf4,
    float4* __restrict__ l2g, float4* __restrict__ org, float4* __restrict__ kpg)
{
    const float* lf = reinterpret_cast<const float*>(bf4);
    const int gbase = tile * IPT;
    const int n_i = min(IPT, Bn - gbase);

    // l2ws: 16 items x 96 f4 = 1536 f4 (24 KB, aligned), 6 exact rounds
    {
        float4* dst = l2g + (size_t)gbase * 96;
        #pragma unroll
        for (int k = 0; k < 6; ++k) {
            const int q  = k * TPB + tid;
            const int i  = q / 96, off = q % 96;
            const int jj = off >> 2, rr = off & 3;
            float4 v;
            if (rr == 3) v = make_float4(0.f, 0.f, 0.f, 1.f);
            else         v = bf4[i * ST + jj * 3 + rr];
            if (i < n_i) dst[q] = v;
        }
    }
    // orient: 16 x 54 f4 = 864 f4 (13.5 KB span, aligned), 3 full + 1 partial
    {
        float4* dst = org + (size_t)gbase * 54;
        #pragma unroll
        for (int k = 0; k < 4; ++k) {
            const int q = k * TPB + tid;
            if (k < 3 || q < 864) {
                float v[4];
                #pragma unroll
                for (int m = 0; m < 4; ++m) {
                    const int f  = q * 4 + m;
                    const int i  = f / 216, r2 = f % 216;
                    const int jj = r2 / 9,  mm = r2 % 9;
                    v[m] = lf[(i * ST + jj * 3 + mm / 3) * 4 + mm % 3];
                }
                if (q / 54 < n_i) dst[q] = make_float4(v[0], v[1], v[2], v[3]);
            }
        }
    }
    // kp3d: 16 x 18 f4 = 288 f4 (4.5 KB span, aligned), 1 full + 1 partial
    {
        float4* dst = kpg + (size_t)gbase * 18;
        #pragma unroll
        for (int k = 0; k < 2; ++k) {
            const int q = k * TPB + tid;
            if (k < 1 || q < 288) {
                float v[4];
                #pragma unroll
                for (int m = 0; m < 4; ++m) {
                    const int f  = q * 4 + m;
                    const int i  = f / 72, r2 = f % 72;
                    const int jj = r2 / 3, rw = r2 % 3;
                    v[m] = lf[(i * ST + jj * 3 + rw) * 4 + 3];
                }
                if (q / 18 < n_i) dst[q] = make_float4(v[0], v[1], v[2], v[3]);
            }
        }
    }
}

__global__ __launch_bounds__(TPB, 4) void fk_kernel(
    const float* __restrict__ theta,
    const float* __restrict__ rest_pose,
    const float* __restrict__ bone_factor,
    float* __restrict__ kp3d,
    float* __restrict__ orient,
    float* __restrict__ l2ws,
    int Bn)
{
    __shared__ float4 buf[2][IPT * ST];        // 2 x 18,688 B = 37,376 B

    const int tid   = threadIdx.x;
    const int tiles = (Bn + IPT - 1) / IPT;
    const int t0    = (tiles + gridDim.x - 1) / gridDim.x;  // tiles per block
    const int start = blockIdx.x * t0;
    const int end   = min(start + t0, tiles);
    if (start >= end) return;

    float4* l2g = reinterpret_cast<float4*>(l2ws);
    float4* org = reinterpret_cast<float4*>(orient);
    float4* kpg = reinterpret_cast<float4*>(kp3d);

    // prologue
    compute_tile(start, Bn, tid, theta, rest_pose, bone_factor, buf[0]);
    __syncthreads();

    // steady state: flush tile i (stores issued first) while computing tile i+1
    for (int i = start; i < end; ++i) {
        const int d = (i - start) & 1;
        flush_tile(i, Bn, tid, buf[d], l2g, org, kpg);
        if (i + 1 < end)
            compute_tile(i + 1, Bn, tid, theta, rest_pose, bone_factor, buf[d ^ 1]);
        __syncthreads();
    }
}

extern "C" void kernel_launch(void* const* d_in, const int* in_sizes, int n_in,
                              void* d_out, int out_size, void* d_ws, size_t ws_size,
                              hipStream_t stream) {
    const float* theta       = (const float*)d_in[0];
    const float* rest_pose   = (const float*)d_in[1];
    const float* bone_factor = (const float*)d_in[2];

    const int Bn = in_sizes[0] / (NJ * 3);
    const size_t BNJ = (size_t)Bn * NJ;

    float* out    = (float*)d_out;
    float* kp3d   = out;                // BNJ*3
    float* orient = out + BNJ * 3;      // BNJ*9
    float* l2ws   = out + BNJ * 12;     // BNJ*16

    const int tiles = (Bn + IPT - 1) / IPT;
    const int grid  = min(NBLK, tiles);
    fk_kernel<<<grid, TPB, 0, stream>>>(theta, rest_pose, bone_factor,
                                        kp3d, orient, l2ws, Bn);
}

// Round 12
// 79.281 us; speedup vs baseline: 1.5614x; 1.5614x over previous
//
#include <hip/hip_runtime.h>
#include <math.h>

#define NJ   24
#define TPB  128
#define IPB  16     // items per block; whole item written in one phase
#define ST   73     // float4 stride per item in LDS (24*3 + 1 pad)

static constexpr int PAR[NJ] = {-1,0,0,0,1,2,3,4,5,6,7,8,9,9,9,12,13,14,16,17,18,19,20,21};

typedef float nfloat4 __attribute__((ext_vector_type(4)));

__device__ __forceinline__ void nt_store(float4* p, float4 v) {
    nfloat4 nv; nv.x = v.x; nv.y = v.y; nv.z = v.z; nv.w = v.w;
    __builtin_nontemporal_store(nv, reinterpret_cast<nfloat4*>(p));
}

__global__ __launch_bounds__(TPB, 3) void fk_kernel(
    const float* __restrict__ theta,        // Bn*NJ*3
    const float* __restrict__ rest_pose,    // NJ*3
    const float* __restrict__ bone_factor,  // NJ-1
    float* __restrict__ kp3d,               // Bn*NJ*3
    float* __restrict__ orient,             // Bn*NJ*9
    float* __restrict__ l2ws,               // Bn*NJ*16
    int Bn)
{
    __shared__ float4 ls[IPB * ST];         // 18,688 B -> ~6 blocks/CU

    const int tid   = threadIdx.x;
    const int item0 = blockIdx.x * IPB;
    if (item0 >= Bn) return;

    // ---------- compute: lane = (item, row), tid<48 (all in wave 0).
    // Rows of the affine chain are independent: row_j = row_par(j) * rel_j.
    const int it  = tid / 3;
    const int row = tid % 3;
    const int gi  = item0 + it;
    if (tid < 48 && gi < Bn) {
        const float4* th4 = reinterpret_cast<const float4*>(theta) + (size_t)gi * 18;
        // single upfront burst: one HBM miss latency for the whole item
        float4 tv[18];
        #pragma unroll
        for (int i = 0; i < 18; ++i) tv[i] = th4[i];

        float4 rows_[NJ];                   // static-indexed; dead elems pruned
        #pragma unroll
        for (int sub = 0; sub < 3; ++sub) {
            float t[24];
            #pragma unroll
            for (int i = 0; i < 6; ++i) {
                const float4 v = tv[sub * 6 + i];
                t[i*4+0] = v.x; t[i*4+1] = v.y; t[i*4+2] = v.z; t[i*4+3] = v.w;
            }
            #pragma unroll
            for (int jj = 0; jj < 8; ++jj) {
                const int j = sub * 8 + jj;        // compile-time constant
                const float x = t[jj*3+0], y = t[jj*3+1], z = t[jj*3+2];
                const float ang = sqrtf(x*x + y*y + z*z + 1e-12f);
                const float inv = 1.0f / ang;
                const float ux = x*inv, uy = y*inv, uz = z*inv;
                const float s  = __sinf(ang);
                const float cs = __cosf(ang);
                const float ic = 1.0f - cs;
                const float xy = ic*ux*uy, xz = ic*ux*uz, yz = ic*uy*uz;
                const float sx = s*ux, sy = s*uy, sz = s*uz;
                const float R00 = cs + ic*ux*ux, R01 = xy - sz, R02 = xz + sy;
                const float R10 = xy + sz, R11 = cs + ic*uy*uy, R12 = yz - sx;
                const float R20 = xz - sy, R21 = yz + sx, R22 = cs + ic*uz*uz;

                float4 p; float bx, by, bz;
                if (j == 0) {
                    p  = make_float4(row == 0 ? 1.f : 0.f,
                                     row == 1 ? 1.f : 0.f,
                                     row == 2 ? 1.f : 0.f, 0.f);
                    bx = rest_pose[0]; by = rest_pose[1]; bz = rest_pose[2];
                } else {
                    p = rows_[PAR[j]];
                    float bfv = bone_factor[j - 1];
                    bfv = sqrtf(bfv*bfv + 1e-36f);
                    bx = (rest_pose[j*3+0] - rest_pose[PAR[j]*3+0]) * bfv;
                    by = (rest_pose[j*3+1] - rest_pose[PAR[j]*3+1]) * bfv;
                    bz = (rest_pose[j*3+2] - rest_pose[PAR[j]*3+2]) * bfv;
                }
                float4 nr;
                nr.x = p.x*R00 + p.y*R10 + p.z*R20;
                nr.y = p.x*R01 + p.y*R11 + p.z*R21;
                nr.z = p.x*R02 + p.y*R12 + p.z*R22;
                nr.w = p.x*bx  + p.y*by  + p.z*bz + p.w;
                rows_[j] = nr;
                ls[it * ST + j * 3 + row] = nr;
            }
        }
    }
    __syncthreads();

    // ---------- flush: whole block's outputs, contiguous + aligned, exactly
    // once, nontemporal (write-once data; keep L2 for theta reads) ----------
    const float* lf = reinterpret_cast<const float*>(ls);
    const int n_i = min(IPB, Bn - item0);

    // l2ws: 16 items x 96 f4 = 1536 f4 (24 KB span, aligned), 12 exact rounds
    {
        float4* dst = reinterpret_cast<float4*>(l2ws) + (size_t)item0 * 96;
        #pragma unroll
        for (int k = 0; k < 12; ++k) {
            const int q  = k * TPB + tid;          // [0,1536)
            const int i  = q / 96, off = q % 96;
            const int jj = off >> 2, rr = off & 3;
            float4 v;
            if (rr == 3) v = make_float4(0.f, 0.f, 0.f, 1.f);
            else         v = ls[i * ST + jj * 3 + rr];
            if (i < n_i) nt_store(&dst[q], v);
        }
    }
    // orient: 16 x 54 f4 = 864 f4 (13.5 KB span, aligned), 6 full + 1 partial
    {
        float4* dst = reinterpret_cast<float4*>(orient) + (size_t)item0 * 54;
        #pragma unroll
        for (int k = 0; k < 7; ++k) {
            const int q = k * TPB + tid;
            if (k < 6 || q < 864) {
                float v[4];
                #pragma unroll
                for (int m = 0; m < 4; ++m) {
                    const int f  = q * 4 + m;       // [0,3456)
                    const int i  = f / 216, r2 = f % 216;
                    const int jj = r2 / 9,  mm = r2 % 9;
                    v[m] = lf[(i * ST + jj * 3 + mm / 3) * 4 + mm % 3];
                }
                if (q / 54 < n_i)
                    nt_store(&dst[q], make_float4(v[0], v[1], v[2], v[3]));
            }
        }
    }
    // kp3d: 16 x 18 f4 = 288 f4 (4.5 KB span, aligned), 2 full + 1 partial
    {
        float4* dst = reinterpret_cast<float4*>(kp3d) + (size_t)item0 * 18;
        #pragma unroll
        for (int k = 0; k < 3; ++k) {
            const int q = k * TPB + tid;
            if (k < 2 || q < 288) {
                float v[4];
                #pragma unroll
                for (int m = 0; m < 4; ++m) {
                    const int f  = q * 4 + m;       // [0,1152)
                    const int i  = f / 72, r2 = f % 72;
                    const int jj = r2 / 3, rw = r2 % 3;
                    v[m] = lf[(i * ST + jj * 3 + rw) * 4 + 3];
                }
                if (q / 18 < n_i)
                    nt_store(&dst[q], make_float4(v[0], v[1], v[2], v[3]));
            }
        }
    }
}

extern "C" void kernel_launch(void* const* d_in, const int* in_sizes, int n_in,
                              void* d_out, int out_size, void* d_ws, size_t ws_size,
                              hipStream_t stream) {
    const float* theta       = (const float*)d_in[0];
    const float* rest_pose   = (const float*)d_in[1];
    const float* bone_factor = (const float*)d_in[2];

    const int Bn = in_sizes[0] / (NJ * 3);
    const size_t BNJ = (size_t)Bn * NJ;

    float* out    = (float*)d_out;
    float* kp3d   = out;                // BNJ*3
    float* orient = out + BNJ * 3;      // BNJ*9
    float* l2ws   = out + BNJ * 12;     // BNJ*16

    const int grid = (Bn + IPB - 1) / IPB;
    fk_kernel<<<grid, TPB, 0, stream>>>(theta, rest_pose, bone_factor,
                                        kp3d, orient, l2ws, Bn);
}

// Round 13
// 72.795 us; speedup vs baseline: 1.7005x; 1.0891x over previous
//
#include <hip/hip_runtime.h>
#include <math.h>

#define NJ   24
#define TPB  64
#define IPB  16     // items per block; whole item written in one phase
#define ST   73     // float4 stride per item in LDS (24*3 + 1 pad)

static constexpr int PAR[NJ] = {-1,0,0,0,1,2,3,4,5,6,7,8,9,9,9,12,13,14,16,17,18,19,20,21};

typedef float nfloat4 __attribute__((ext_vector_type(4)));

__device__ __forceinline__ void nt_store(float4* p, float4 v) {
    nfloat4 nv; nv.x = v.x; nv.y = v.y; nv.z = v.z; nv.w = v.w;
    __builtin_nontemporal_store(nv, reinterpret_cast<nfloat4*>(p));
}

__global__ __launch_bounds__(TPB, 2) void fk_kernel(
    const float* __restrict__ theta,        // Bn*NJ*3
    const float* __restrict__ rest_pose,    // NJ*3
    const float* __restrict__ bone_factor,  // NJ-1
    float* __restrict__ kp3d,               // Bn*NJ*3
    float* __restrict__ orient,             // Bn*NJ*9
    float* __restrict__ l2ws,               // Bn*NJ*16
    int Bn)
{
    __shared__ float4 ls[IPB * ST];         // 18,688 B -> 8 blocks/CU (LDS cap)

    const int tid   = threadIdx.x;
    const int item0 = blockIdx.x * IPB;
    if (item0 >= Bn) return;

    // ---------- compute: lane = (item, row), tid<48; single wave.
    // Rows of the affine chain are independent: row_j = row_par(j) * rel_j.
    const int it  = tid / 3;
    const int row = tid % 3;
    const int gi  = item0 + it;
    if (tid < 48 && gi < Bn) {
        const float4* th4 = reinterpret_cast<const float4*>(theta) + (size_t)gi * 18;
        // single upfront burst: one HBM miss latency for the whole item
        float4 tv[18];
        #pragma unroll
        for (int i = 0; i < 18; ++i) tv[i] = th4[i];

        float4 rows_[NJ];                   // static-indexed; dead elems pruned
        #pragma unroll
        for (int sub = 0; sub < 3; ++sub) {
            float t[24];
            #pragma unroll
            for (int i = 0; i < 6; ++i) {
                const float4 v = tv[sub * 6 + i];
                t[i*4+0] = v.x; t[i*4+1] = v.y; t[i*4+2] = v.z; t[i*4+3] = v.w;
            }
            #pragma unroll
            for (int jj = 0; jj < 8; ++jj) {
                const int j = sub * 8 + jj;        // compile-time constant
                const float x = t[jj*3+0], y = t[jj*3+1], z = t[jj*3+2];
                const float ang = sqrtf(x*x + y*y + z*z + 1e-12f);
                const float inv = 1.0f / ang;
                const float ux = x*inv, uy = y*inv, uz = z*inv;
                const float s  = __sinf(ang);
                const float cs = __cosf(ang);
                const float ic = 1.0f - cs;
                const float xy = ic*ux*uy, xz = ic*ux*uz, yz = ic*uy*uz;
                const float sx = s*ux, sy = s*uy, sz = s*uz;
                const float R00 = cs + ic*ux*ux, R01 = xy - sz, R02 = xz + sy;
                const float R10 = xy + sz, R11 = cs + ic*uy*uy, R12 = yz - sx;
                const float R20 = xz - sy, R21 = yz + sx, R22 = cs + ic*uz*uz;

                float4 p; float bx, by, bz;
                if (j == 0) {
                    p  = make_float4(row == 0 ? 1.f : 0.f,
                                     row == 1 ? 1.f : 0.f,
                                     row == 2 ? 1.f : 0.f, 0.f);
                    bx = rest_pose[0]; by = rest_pose[1]; bz = rest_pose[2];
                } else {
                    p = rows_[PAR[j]];
                    float bfv = bone_factor[j - 1];
                    bfv = sqrtf(bfv*bfv + 1e-36f);
                    bx = (rest_pose[j*3+0] - rest_pose[PAR[j]*3+0]) * bfv;
                    by = (rest_pose[j*3+1] - rest_pose[PAR[j]*3+1]) * bfv;
                    bz = (rest_pose[j*3+2] - rest_pose[PAR[j]*3+2]) * bfv;
                }
                float4 nr;
                nr.x = p.x*R00 + p.y*R10 + p.z*R20;
                nr.y = p.x*R01 + p.y*R11 + p.z*R21;
                nr.z = p.x*R02 + p.y*R12 + p.z*R22;
                nr.w = p.x*bx  + p.y*by  + p.z*bz + p.w;
                rows_[j] = nr;
                ls[it * ST + j * 3 + row] = nr;
            }
        }
    }
    __syncthreads();   // single-wave block: compiles to a cheap s_barrier

    // ---------- flush: whole block's outputs, contiguous + aligned, exactly
    // once, nontemporal (write-once data; keep L2 for theta reads) ----------
    const float* lf = reinterpret_cast<const float*>(ls);
    const int n_i = min(IPB, Bn - item0);

    // l2ws: 16 items x 96 f4 = 1536 f4 (24 KB span, aligned), 24 exact rounds
    {
        float4* dst = reinterpret_cast<float4*>(l2ws) + (size_t)item0 * 96;
        #pragma unroll
        for (int k = 0; k < 24; ++k) {
            const int q  = k * TPB + tid;          // [0,1536)
            const int i  = q / 96, off = q % 96;
            const int jj = off >> 2, rr = off & 3;
            float4 v;
            if (rr == 3) v = make_float4(0.f, 0.f, 0.f, 1.f);
            else         v = ls[i * ST + jj * 3 + rr];
            if (i < n_i) nt_store(&dst[q], v);
        }
    }
    // orient: 16 x 54 f4 = 864 f4 (13.5 KB span, aligned), 13 full + 1 partial
    {
        float4* dst = reinterpret_cast<float4*>(orient) + (size_t)item0 * 54;
        #pragma unroll
        for (int k = 0; k < 14; ++k) {
            const int q = k * TPB + tid;
            if (k < 13 || q < 864) {
                float v[4];
                #pragma unroll
                for (int m = 0; m < 4; ++m) {
                    const int f  = q * 4 + m;       // [0,3456)
                    const int i  = f / 216, r2 = f % 216;
                    const int jj = r2 / 9,  mm = r2 % 9;
                    v[m] = lf[(i * ST + jj * 3 + mm / 3) * 4 + mm % 3];
                }
                if (q / 54 < n_i)
                    nt_store(&dst[q], make_float4(v[0], v[1], v[2], v[3]));
            }
        }
    }
    // kp3d: 16 x 18 f4 = 288 f4 (4.5 KB span, aligned), 4 full + 1 partial
    {
        float4* dst = reinterpret_cast<float4*>(kp3d) + (size_t)item0 * 18;
        #pragma unroll
        for (int k = 0; k < 5; ++k) {
            const int q = k * TPB + tid;
            if (k < 4 || q < 288) {
                float v[4];
                #pragma unroll
                for (int m = 0; m < 4; ++m) {
                    const int f  = q * 4 + m;       // [0,1152)
                    const int i  = f / 72, r2 = f % 72;
                    const int jj = r2 / 3, rw = r2 % 3;
                    v[m] = lf[(i * ST + jj * 3 + rw) * 4 + 3];
                }
                if (q / 18 < n_i)
                    nt_store(&dst[q], make_float4(v[0], v[1], v[2], v[3]));
            }
        }
    }
}

extern "C" void kernel_launch(void* const* d_in, const int* in_sizes, int n_in,
                              void* d_out, int out_size, void* d_ws, size_t ws_size,
                              hipStream_t stream) {
    const float* theta       = (const float*)d_in[0];
    const float* rest_pose   = (const float*)d_in[1];
    const float* bone_factor = (const float*)d_in[2];

    const int Bn = in_sizes[0] / (NJ * 3);
    const size_t BNJ = (size_t)Bn * NJ;

    float* out    = (float*)d_out;
    float* kp3d   = out;                // BNJ*3
    float* orient = out + BNJ * 3;      // BNJ*9
    float* l2ws   = out + BNJ * 12;     // BNJ*16

    const int grid = (Bn + IPB - 1) / IPB;
    fk_kernel<<<grid, TPB, 0, stream>>>(theta, rest_pose, bone_factor,
                                        kp3d, orient, l2ws, Bn);
}